// Round 7
// baseline (86.774 us; speedup 1.0000x reference)
//
#include <hip/hip_runtime.h>

#define D_FEAT 64
#define MAX_K 8
#define ROWPTR_BLOCKS 256
#define COMBINE_BLOCKS 2048

__device__ __forceinline__ unsigned short f2bf_rne(float f) {
    unsigned int u = __float_as_uint(f);
    u += 0x7FFFu + ((u >> 16) & 1u);   // round-to-nearest-even
    return (unsigned short)(u >> 16);
}

__device__ __forceinline__ float bf_lo(unsigned int d) { return __uint_as_float(d << 16); }
__device__ __forceinline__ float bf_hi(unsigned int d) { return __uint_as_float(d & 0xffff0000u); }

// Kernel 1 (fused): blocks [0, ROWPTR_BLOCKS) build CSR row_ptr (dispatched
// FIRST so this short stream hides under combine's HBM stream). Remaining
// blocks build combined_bf16 = bf16(sum_k max(w_k,0)*h_ops[k]), skipping
// w_k<=0 planes; loads and FMAs phased so surviving loads issue back-to-back.
__global__ __launch_bounds__(256) void combine_rowptr_kernel(
    const float* __restrict__ h_ops,
    const float* __restrict__ weights,
    unsigned short* __restrict__ combined,
    const int* __restrict__ row,
    int* __restrict__ row_ptr,
    int total4, int K, int E, int N) {
    if (blockIdx.x < ROWPTR_BLOCKS) {
        int stride = ROWPTR_BLOCKS * 256;
        for (int e = blockIdx.x * 256 + threadIdx.x; e < E; e += stride) {
            int r = row[e];
            int rp = (e == 0) ? -1 : row[e - 1];
            for (int x = rp + 1; x <= r; ++x) row_ptr[x] = e;
            if (e == E - 1) {
                for (int x = r + 1; x <= N; ++x) row_ptr[x] = E;
            }
        }
    } else {
        float w[MAX_K];
#pragma unroll
        for (int k = 0; k < MAX_K; ++k) {
            float wk = (k < K) ? weights[k] : 0.f;
            w[k] = wk > 0.f ? wk : 0.f;
        }
        int stride = COMBINE_BLOCKS * 256;
        for (int i = (blockIdx.x - ROWPTR_BLOCKS) * 256 + threadIdx.x; i < total4; i += stride) {
            float4 v[MAX_K];
#pragma unroll
            for (int k = 0; k < MAX_K; ++k) {
                if (w[k] != 0.f) {
                    v[k] = reinterpret_cast<const float4*>(h_ops)[(size_t)k * total4 + i];
                }
            }
            float4 acc = make_float4(0.f, 0.f, 0.f, 0.f);
#pragma unroll
            for (int k = 0; k < MAX_K; ++k) {
                if (w[k] != 0.f) {
                    acc.x = fmaf(w[k], v[k].x, acc.x);
                    acc.y = fmaf(w[k], v[k].y, acc.y);
                    acc.z = fmaf(w[k], v[k].z, acc.z);
                    acc.w = fmaf(w[k], v[k].w, acc.w);
                }
            }
            ushort4 o;
            o.x = f2bf_rne(acc.x); o.y = f2bf_rne(acc.y);
            o.z = f2bf_rne(acc.z); o.w = f2bf_rne(acc.w);
            reinterpret_cast<ushort4*>(combined)[i] = o;
        }
    }
}

// Kernel 2: one wave per node. 8-lane cluster per edge slot: sub=lane>>3 picks
// the edge, fl=lane&7 picks a 16 B feature slice; one dwordx4 gather covers 8
// edges. Main loop peeled to FULL 16-edge iterations (no clamps/masks -> no
// wasted fetches); epilogue uses exec-masked gathers (masked lanes issue no
// requests, unlike clamping which fetched real garbage rows).
__global__ __launch_bounds__(256) void spmm_bf16_w8_kernel(
    const unsigned short* __restrict__ combined,
    const float* __restrict__ vals,
    const int* __restrict__ row_ptr,
    const int* __restrict__ col,
    const float* __restrict__ weights,
    float* __restrict__ out,
    int n_nodes, int K) {
    int wid = (blockIdx.x * blockDim.x + threadIdx.x) >> 6;
    int lane = threadIdx.x & 63;
    if (wid >= n_nodes) return;

    float s = 0.f;
    for (int k = 0; k < K; ++k) {
        float wk = weights[k];
        if (!(wk > 0.f)) s += wk;
    }

    int start = row_ptr[wid];
    int end   = row_ptr[wid + 1];
    int cnt   = end - start;

    int sub = lane >> 3;   // edge slot within group of 8
    int fl  = lane & 7;    // 16 B feature slice

    float a0 = 0.f, a1 = 0.f, a2 = 0.f, a3 = 0.f;
    float a4 = 0.f, a5 = 0.f, a6 = 0.f, a7 = 0.f;

    const uint4* cb = reinterpret_cast<const uint4*>(combined);

    // ---- main loop: full 16-edge iterations, branch/clamp-free ----
    int nfull = cnt >> 4;
    int base = start;
    for (int it = 0; it < nfull; ++it, base += 16) {
        int iA = base + sub;
        int iB = base + 8 + sub;
        int cA = col[iA];
        int cB = col[iB];
        float vA = vals[iA];
        float vB = vals[iB];
        uint4 gA = cb[((size_t)cA << 3) + fl];
        uint4 gB = cb[((size_t)cB << 3) + fl];
        a0 = fmaf(vA, bf_lo(gA.x), a0); a1 = fmaf(vA, bf_hi(gA.x), a1);
        a2 = fmaf(vA, bf_lo(gA.y), a2); a3 = fmaf(vA, bf_hi(gA.y), a3);
        a4 = fmaf(vA, bf_lo(gA.z), a4); a5 = fmaf(vA, bf_hi(gA.z), a5);
        a6 = fmaf(vA, bf_lo(gA.w), a6); a7 = fmaf(vA, bf_hi(gA.w), a7);
        a0 = fmaf(vB, bf_lo(gB.x), a0); a1 = fmaf(vB, bf_hi(gB.x), a1);
        a2 = fmaf(vB, bf_lo(gB.y), a2); a3 = fmaf(vB, bf_hi(gB.y), a3);
        a4 = fmaf(vB, bf_lo(gB.z), a4); a5 = fmaf(vB, bf_hi(gB.z), a5);
        a6 = fmaf(vB, bf_lo(gB.w), a6); a7 = fmaf(vB, bf_hi(gB.w), a7);
    }

    // ---- epilogue: remainder < 16 edges, exec-masked gathers ----
    if (base < end) {
        int iA = base + sub;
        int iB = base + 8 + sub;
        bool okA = iA < end;
        bool okB = iB < end;
        int iAc = okA ? iA : end - 1;   // clamp ok for 4 B metadata loads
        int iBc = okB ? iB : end - 1;
        int cA = col[iAc];
        int cB = col[iBc];
        float vA = okA ? vals[iAc] : 0.f;
        float vB = okB ? vals[iBc] : 0.f;
        uint4 gA; gA.x = gA.y = gA.z = gA.w = 0u;
        uint4 gB; gB.x = gB.y = gB.z = gB.w = 0u;
        if (okA) gA = cb[((size_t)cA << 3) + fl];   // masked lanes: no request
        if (okB) gB = cb[((size_t)cB << 3) + fl];
        a0 = fmaf(vA, bf_lo(gA.x), a0); a1 = fmaf(vA, bf_hi(gA.x), a1);
        a2 = fmaf(vA, bf_lo(gA.y), a2); a3 = fmaf(vA, bf_hi(gA.y), a3);
        a4 = fmaf(vA, bf_lo(gA.z), a4); a5 = fmaf(vA, bf_hi(gA.z), a5);
        a6 = fmaf(vA, bf_lo(gA.w), a6); a7 = fmaf(vA, bf_hi(gA.w), a7);
        a0 = fmaf(vB, bf_lo(gB.x), a0); a1 = fmaf(vB, bf_hi(gB.x), a1);
        a2 = fmaf(vB, bf_lo(gB.y), a2); a3 = fmaf(vB, bf_hi(gB.y), a3);
        a4 = fmaf(vB, bf_lo(gB.z), a4); a5 = fmaf(vB, bf_hi(gB.z), a5);
        a6 = fmaf(vB, bf_lo(gB.w), a6); a7 = fmaf(vB, bf_hi(gB.w), a7);
    }

    // reduce across the 8 edge slots (lanes fl, fl+8, ..., fl+56)
#pragma unroll
    for (int m = 8; m <= 32; m <<= 1) {
        a0 += __shfl_xor(a0, m, 64);
        a1 += __shfl_xor(a1, m, 64);
        a2 += __shfl_xor(a2, m, 64);
        a3 += __shfl_xor(a3, m, 64);
        a4 += __shfl_xor(a4, m, 64);
        a5 += __shfl_xor(a5, m, 64);
        a6 += __shfl_xor(a6, m, 64);
        a7 += __shfl_xor(a7, m, 64);
    }

    if (sub == 0) {
        float4* po = reinterpret_cast<float4*>(out + (size_t)wid * D_FEAT + fl * 8);
        po[0] = make_float4(a0 + s, a1 + s, a2 + s, a3 + s);
        po[1] = make_float4(a4 + s, a5 + s, a6 + s, a7 + s);
    }
}

// Fallback (small ws): fp32 combined + binary search.
__global__ __launch_bounds__(256) void combine_kernel(
    const float* __restrict__ h_ops,
    const float* __restrict__ weights,
    float* __restrict__ combined,
    int total4, int K) {
    float w[MAX_K];
    for (int k = 0; k < K; ++k) {
        float wk = weights[k];
        w[k] = wk > 0.f ? wk : 0.f;
    }
    int stride = gridDim.x * blockDim.x;
    for (int i = blockIdx.x * blockDim.x + threadIdx.x; i < total4; i += stride) {
        float4 acc = make_float4(0.f, 0.f, 0.f, 0.f);
        for (int k = 0; k < K; ++k) {
            if (w[k] != 0.f) {
                float4 v = reinterpret_cast<const float4*>(h_ops)[(size_t)k * total4 + i];
                acc.x = fmaf(w[k], v.x, acc.x);
                acc.y = fmaf(w[k], v.y, acc.y);
                acc.z = fmaf(w[k], v.z, acc.z);
                acc.w = fmaf(w[k], v.w, acc.w);
            }
        }
        reinterpret_cast<float4*>(combined)[i] = acc;
    }
}

__global__ __launch_bounds__(256) void spmm_kernel_bs(
    const float* __restrict__ combined,
    const float* __restrict__ vals,
    const int* __restrict__ row,
    const int* __restrict__ col,
    const float* __restrict__ weights,
    float* __restrict__ out,
    int n_nodes, int n_edges, int K) {
    int wid = (blockIdx.x * blockDim.x + threadIdx.x) >> 6;
    int lane = threadIdx.x & 63;
    if (wid >= n_nodes) return;

    int lo = 0, hi = n_edges;
    while (lo < hi) { int mid = (lo + hi) >> 1; if (row[mid] < wid) lo = mid + 1; else hi = mid; }
    int start = lo;
    hi = n_edges;
    while (lo < hi) { int mid = (lo + hi) >> 1; if (row[mid] <= wid) lo = mid + 1; else hi = mid; }
    int end = lo;

    float acc = 0.f;
    for (int e = start; e < end; ++e) {
        acc = fmaf(vals[e], combined[(size_t)col[e] * D_FEAT + lane], acc);
    }
    float s = 0.f;
    for (int k = 0; k < K; ++k) {
        float wk = weights[k];
        if (!(wk > 0.f)) s += wk;
    }
    out[(size_t)wid * D_FEAT + lane] = acc + s;
}

// Last-resort fallback: recompute combined per edge (tiny workspace).
__global__ __launch_bounds__(256) void spmm_fused_kernel(
    const float* __restrict__ h_ops,
    const float* __restrict__ vals,
    const int* __restrict__ row,
    const int* __restrict__ col,
    const float* __restrict__ weights,
    float* __restrict__ out,
    int n_nodes, int n_edges, int K, size_t plane) {
    int wid = (blockIdx.x * blockDim.x + threadIdx.x) >> 6;
    int lane = threadIdx.x & 63;
    if (wid >= n_nodes) return;

    float w[MAX_K];
    for (int k = 0; k < K; ++k) {
        float wk = weights[k];
        w[k] = wk > 0.f ? wk : 0.f;
    }
    int lo = 0, hi = n_edges;
    while (lo < hi) { int mid = (lo + hi) >> 1; if (row[mid] < wid) lo = mid + 1; else hi = mid; }
    int start = lo;
    hi = n_edges;
    while (lo < hi) { int mid = (lo + hi) >> 1; if (row[mid] <= wid) lo = mid + 1; else hi = mid; }
    int end = lo;

    float acc = 0.f;
    for (int e = start; e < end; ++e) {
        int c = col[e];
        float v = vals[e];
        float comb = 0.f;
        for (int k = 0; k < K; ++k) {
            comb = fmaf(w[k], h_ops[(size_t)k * plane + (size_t)c * D_FEAT + lane], comb);
        }
        acc = fmaf(v, comb, acc);
    }
    float s = 0.f;
    for (int k = 0; k < K; ++k) {
        float wk = weights[k];
        if (!(wk > 0.f)) s += wk;
    }
    out[(size_t)wid * D_FEAT + lane] = acc + s;
}

extern "C" void kernel_launch(void* const* d_in, const int* in_sizes, int n_in,
                              void* d_out, int out_size, void* d_ws, size_t ws_size,
                              hipStream_t stream) {
    const float* h_ops   = (const float*)d_in[0];
    const float* weights = (const float*)d_in[1];
    const float* vals    = (const float*)d_in[2];
    const int*   row     = (const int*)d_in[3];
    const int*   col     = (const int*)d_in[4];
    float* out = (float*)d_out;

    int K = in_sizes[1];
    if (K > MAX_K) K = MAX_K;
    int E = in_sizes[2];
    int N = out_size / D_FEAT;
    int total = N * D_FEAT;
    size_t need_bf      = (size_t)total * sizeof(unsigned short);
    size_t need_rowptr  = (size_t)(N + 1) * sizeof(int);
    size_t need_f32     = (size_t)total * sizeof(float);

    int spmm_blocks = (N * 64 + 255) / 256;  // 4 waves (nodes) per block

    if (ws_size >= need_bf + need_rowptr) {
        unsigned short* combined = (unsigned short*)d_ws;
        int* row_ptr = (int*)((char*)d_ws + need_bf);
        int total4 = total / 4;
        combine_rowptr_kernel<<<ROWPTR_BLOCKS + COMBINE_BLOCKS, 256, 0, stream>>>(
            h_ops, weights, combined, row, row_ptr, total4, K, E, N);
        spmm_bf16_w8_kernel<<<spmm_blocks, 256, 0, stream>>>(combined, vals, row_ptr, col,
                                                             weights, out, N, K);
    } else if (ws_size >= need_f32) {
        float* combined = (float*)d_ws;
        int total4 = total / 4;
        combine_kernel<<<2048, 256, 0, stream>>>(h_ops, weights, combined, total4, K);
        spmm_kernel_bs<<<spmm_blocks, 256, 0, stream>>>(combined, vals, row, col,
                                                        weights, out, N, E, K);
    } else {
        spmm_fused_kernel<<<spmm_blocks, 256, 0, stream>>>(h_ops, vals, row, col, weights,
                                                           out, N, E, K, (size_t)total);
    }
}

// Round 8
// 84.559 us; speedup vs baseline: 1.0262x; 1.0262x over previous
//
#include <hip/hip_runtime.h>

#define D_FEAT 64
#define MAX_K 8
#define ROWPTR_BLOCKS 256
#define COMBINE_BLOCKS 2048

__device__ __forceinline__ unsigned short f2bf_rne(float f) {
    unsigned int u = __float_as_uint(f);
    u += 0x7FFFu + ((u >> 16) & 1u);   // round-to-nearest-even
    return (unsigned short)(u >> 16);
}

__device__ __forceinline__ float bf_lo(unsigned int d) { return __uint_as_float(d << 16); }
__device__ __forceinline__ float bf_hi(unsigned int d) { return __uint_as_float(d & 0xffff0000u); }

// Kernel 1 (fused): blocks [0, ROWPTR_BLOCKS) build CSR row_ptr (dispatched
// FIRST so this short stream hides under combine's HBM stream). Remaining
// blocks build combined_bf16 = bf16(sum_k max(w_k,0)*h_ops[k]), skipping
// w_k<=0 planes; loads and FMAs phased so surviving loads issue back-to-back.
__global__ __launch_bounds__(256) void combine_rowptr_kernel(
    const float* __restrict__ h_ops,
    const float* __restrict__ weights,
    unsigned short* __restrict__ combined,
    const int* __restrict__ row,
    int* __restrict__ row_ptr,
    int total4, int K, int E, int N) {
    if (blockIdx.x < ROWPTR_BLOCKS) {
        int stride = ROWPTR_BLOCKS * 256;
        for (int e = blockIdx.x * 256 + threadIdx.x; e < E; e += stride) {
            int r = row[e];
            int rp = (e == 0) ? -1 : row[e - 1];
            for (int x = rp + 1; x <= r; ++x) row_ptr[x] = e;
            if (e == E - 1) {
                for (int x = r + 1; x <= N; ++x) row_ptr[x] = E;
            }
        }
    } else {
        float w[MAX_K];
#pragma unroll
        for (int k = 0; k < MAX_K; ++k) {
            float wk = (k < K) ? weights[k] : 0.f;
            w[k] = wk > 0.f ? wk : 0.f;
        }
        int stride = COMBINE_BLOCKS * 256;
        for (int i = (blockIdx.x - ROWPTR_BLOCKS) * 256 + threadIdx.x; i < total4; i += stride) {
            float4 v[MAX_K];
#pragma unroll
            for (int k = 0; k < MAX_K; ++k) {
                if (w[k] != 0.f) {
                    v[k] = reinterpret_cast<const float4*>(h_ops)[(size_t)k * total4 + i];
                }
            }
            float4 acc = make_float4(0.f, 0.f, 0.f, 0.f);
#pragma unroll
            for (int k = 0; k < MAX_K; ++k) {
                if (w[k] != 0.f) {
                    acc.x = fmaf(w[k], v[k].x, acc.x);
                    acc.y = fmaf(w[k], v[k].y, acc.y);
                    acc.z = fmaf(w[k], v[k].z, acc.z);
                    acc.w = fmaf(w[k], v[k].w, acc.w);
                }
            }
            ushort4 o;
            o.x = f2bf_rne(acc.x); o.y = f2bf_rne(acc.y);
            o.z = f2bf_rne(acc.z); o.w = f2bf_rne(acc.w);
            reinterpret_cast<ushort4*>(combined)[i] = o;
        }
    }
}

// FMA helper: accumulate 8 bf16 features of one gathered fragment.
#define FRAG_FMA(v, g)                                                          \
    a0 = fmaf(v, bf_lo((g).x), a0); a1 = fmaf(v, bf_hi((g).x), a1);             \
    a2 = fmaf(v, bf_lo((g).y), a2); a3 = fmaf(v, bf_hi((g).y), a3);             \
    a4 = fmaf(v, bf_lo((g).z), a4); a5 = fmaf(v, bf_hi((g).z), a5);             \
    a6 = fmaf(v, bf_lo((g).w), a6); a7 = fmaf(v, bf_hi((g).w), a7);

// Kernel 2: one wave per node. 8-lane cluster per edge slot: sub=lane>>3 picks
// the edge, fl=lane&7 picks a 16 B feature slice; one dwordx4 gather covers 8
// edges. Main loop = branch-free 32-edge iterations with FOUR independent
// gathers in flight (MLP A/B vs R6's two). Remainder >=16 handled by one
// unconditional 16-edge block; <16 by an exec-masked epilogue.
__global__ __launch_bounds__(256) void spmm_bf16_w8_kernel(
    const unsigned short* __restrict__ combined,
    const float* __restrict__ vals,
    const int* __restrict__ row_ptr,
    const int* __restrict__ col,
    const float* __restrict__ weights,
    float* __restrict__ out,
    int n_nodes, int K) {
    int wid = (blockIdx.x * blockDim.x + threadIdx.x) >> 6;
    int lane = threadIdx.x & 63;
    if (wid >= n_nodes) return;

    float s = 0.f;
    for (int k = 0; k < K; ++k) {
        float wk = weights[k];
        if (!(wk > 0.f)) s += wk;
    }

    int start = row_ptr[wid];
    int end   = row_ptr[wid + 1];
    int cnt   = end - start;

    int sub = lane >> 3;   // edge slot within group of 8
    int fl  = lane & 7;    // 16 B feature slice

    float a0 = 0.f, a1 = 0.f, a2 = 0.f, a3 = 0.f;
    float a4 = 0.f, a5 = 0.f, a6 = 0.f, a7 = 0.f;

    const uint4* cb = reinterpret_cast<const uint4*>(combined);

    // ---- main loop: full 32-edge iterations, 4 gathers in flight ----
    int base = start;
    int n32 = cnt >> 5;
    for (int it = 0; it < n32; ++it, base += 32) {
        int i0 = base + sub;
        int i1 = base + 8 + sub;
        int i2 = base + 16 + sub;
        int i3 = base + 24 + sub;
        int c0 = col[i0], c1 = col[i1], c2 = col[i2], c3 = col[i3];
        float v0 = vals[i0], v1 = vals[i1], v2 = vals[i2], v3 = vals[i3];
        uint4 g0 = cb[((size_t)c0 << 3) + fl];
        uint4 g1 = cb[((size_t)c1 << 3) + fl];
        uint4 g2 = cb[((size_t)c2 << 3) + fl];
        uint4 g3 = cb[((size_t)c3 << 3) + fl];
        FRAG_FMA(v0, g0)
        FRAG_FMA(v1, g1)
        FRAG_FMA(v2, g2)
        FRAG_FMA(v3, g3)
    }

    // ---- one unconditional 16-edge block if remainder >= 16 ----
    if (end - base >= 16) {
        int i0 = base + sub;
        int i1 = base + 8 + sub;
        int c0 = col[i0], c1 = col[i1];
        float v0 = vals[i0], v1 = vals[i1];
        uint4 g0 = cb[((size_t)c0 << 3) + fl];
        uint4 g1 = cb[((size_t)c1 << 3) + fl];
        FRAG_FMA(v0, g0)
        FRAG_FMA(v1, g1)
        base += 16;
    }

    // ---- epilogue: remainder < 16 edges, exec-masked gathers ----
    if (base < end) {
        int i0 = base + sub;
        int i1 = base + 8 + sub;
        bool ok0 = i0 < end;
        bool ok1 = i1 < end;
        int i0c = ok0 ? i0 : end - 1;   // clamp ok for 4 B metadata loads
        int i1c = ok1 ? i1 : end - 1;
        int c0 = col[i0c];
        int c1 = col[i1c];
        float v0 = ok0 ? vals[i0c] : 0.f;
        float v1 = ok1 ? vals[i1c] : 0.f;
        uint4 g0; g0.x = g0.y = g0.z = g0.w = 0u;
        uint4 g1; g1.x = g1.y = g1.z = g1.w = 0u;
        if (ok0) g0 = cb[((size_t)c0 << 3) + fl];   // masked lanes: no request
        if (ok1) g1 = cb[((size_t)c1 << 3) + fl];
        FRAG_FMA(v0, g0)
        FRAG_FMA(v1, g1)
    }

    // reduce across the 8 edge slots (lanes fl, fl+8, ..., fl+56)
#pragma unroll
    for (int m = 8; m <= 32; m <<= 1) {
        a0 += __shfl_xor(a0, m, 64);
        a1 += __shfl_xor(a1, m, 64);
        a2 += __shfl_xor(a2, m, 64);
        a3 += __shfl_xor(a3, m, 64);
        a4 += __shfl_xor(a4, m, 64);
        a5 += __shfl_xor(a5, m, 64);
        a6 += __shfl_xor(a6, m, 64);
        a7 += __shfl_xor(a7, m, 64);
    }

    if (sub == 0) {
        float4* po = reinterpret_cast<float4*>(out + (size_t)wid * D_FEAT + fl * 8);
        po[0] = make_float4(a0 + s, a1 + s, a2 + s, a3 + s);
        po[1] = make_float4(a4 + s, a5 + s, a6 + s, a7 + s);
    }
}

// Fallback (small ws): fp32 combined + binary search.
__global__ __launch_bounds__(256) void combine_kernel(
    const float* __restrict__ h_ops,
    const float* __restrict__ weights,
    float* __restrict__ combined,
    int total4, int K) {
    float w[MAX_K];
    for (int k = 0; k < K; ++k) {
        float wk = weights[k];
        w[k] = wk > 0.f ? wk : 0.f;
    }
    int stride = gridDim.x * blockDim.x;
    for (int i = blockIdx.x * blockDim.x + threadIdx.x; i < total4; i += stride) {
        float4 acc = make_float4(0.f, 0.f, 0.f, 0.f);
        for (int k = 0; k < K; ++k) {
            if (w[k] != 0.f) {
                float4 v = reinterpret_cast<const float4*>(h_ops)[(size_t)k * total4 + i];
                acc.x = fmaf(w[k], v.x, acc.x);
                acc.y = fmaf(w[k], v.y, acc.y);
                acc.z = fmaf(w[k], v.z, acc.z);
                acc.w = fmaf(w[k], v.w, acc.w);
            }
        }
        reinterpret_cast<float4*>(combined)[i] = acc;
    }
}

__global__ __launch_bounds__(256) void spmm_kernel_bs(
    const float* __restrict__ combined,
    const float* __restrict__ vals,
    const int* __restrict__ row,
    const int* __restrict__ col,
    const float* __restrict__ weights,
    float* __restrict__ out,
    int n_nodes, int n_edges, int K) {
    int wid = (blockIdx.x * blockDim.x + threadIdx.x) >> 6;
    int lane = threadIdx.x & 63;
    if (wid >= n_nodes) return;

    int lo = 0, hi = n_edges;
    while (lo < hi) { int mid = (lo + hi) >> 1; if (row[mid] < wid) lo = mid + 1; else hi = mid; }
    int start = lo;
    hi = n_edges;
    while (lo < hi) { int mid = (lo + hi) >> 1; if (row[mid] <= wid) lo = mid + 1; else hi = mid; }
    int end = lo;

    float acc = 0.f;
    for (int e = start; e < end; ++e) {
        acc = fmaf(vals[e], combined[(size_t)col[e] * D_FEAT + lane], acc);
    }
    float s = 0.f;
    for (int k = 0; k < K; ++k) {
        float wk = weights[k];
        if (!(wk > 0.f)) s += wk;
    }
    out[(size_t)wid * D_FEAT + lane] = acc + s;
}

// Last-resort fallback: recompute combined per edge (tiny workspace).
__global__ __launch_bounds__(256) void spmm_fused_kernel(
    const float* __restrict__ h_ops,
    const float* __restrict__ vals,
    const int* __restrict__ row,
    const int* __restrict__ col,
    const float* __restrict__ weights,
    float* __restrict__ out,
    int n_nodes, int n_edges, int K, size_t plane) {
    int wid = (blockIdx.x * blockDim.x + threadIdx.x) >> 6;
    int lane = threadIdx.x & 63;
    if (wid >= n_nodes) return;

    float w[MAX_K];
    for (int k = 0; k < K; ++k) {
        float wk = weights[k];
        w[k] = wk > 0.f ? wk : 0.f;
    }
    int lo = 0, hi = n_edges;
    while (lo < hi) { int mid = (lo + hi) >> 1; if (row[mid] < wid) lo = mid + 1; else hi = mid; }
    int start = lo;
    hi = n_edges;
    while (lo < hi) { int mid = (lo + hi) >> 1; if (row[mid] <= wid) lo = mid + 1; else hi = mid; }
    int end = lo;

    float acc = 0.f;
    for (int e = start; e < end; ++e) {
        int c = col[e];
        float v = vals[e];
        float comb = 0.f;
        for (int k = 0; k < K; ++k) {
            comb = fmaf(w[k], h_ops[(size_t)k * plane + (size_t)c * D_FEAT + lane], comb);
        }
        acc = fmaf(v, comb, acc);
    }
    float s = 0.f;
    for (int k = 0; k < K; ++k) {
        float wk = weights[k];
        if (!(wk > 0.f)) s += wk;
    }
    out[(size_t)wid * D_FEAT + lane] = acc + s;
}

extern "C" void kernel_launch(void* const* d_in, const int* in_sizes, int n_in,
                              void* d_out, int out_size, void* d_ws, size_t ws_size,
                              hipStream_t stream) {
    const float* h_ops   = (const float*)d_in[0];
    const float* weights = (const float*)d_in[1];
    const float* vals    = (const float*)d_in[2];
    const int*   row     = (const int*)d_in[3];
    const int*   col     = (const int*)d_in[4];
    float* out = (float*)d_out;

    int K = in_sizes[1];
    if (K > MAX_K) K = MAX_K;
    int E = in_sizes[2];
    int N = out_size / D_FEAT;
    int total = N * D_FEAT;
    size_t need_bf      = (size_t)total * sizeof(unsigned short);
    size_t need_rowptr  = (size_t)(N + 1) * sizeof(int);
    size_t need_f32     = (size_t)total * sizeof(float);

    int spmm_blocks = (N * 64 + 255) / 256;  // 4 waves (nodes) per block

    if (ws_size >= need_bf + need_rowptr) {
        unsigned short* combined = (unsigned short*)d_ws;
        int* row_ptr = (int*)((char*)d_ws + need_bf);
        int total4 = total / 4;
        combine_rowptr_kernel<<<ROWPTR_BLOCKS + COMBINE_BLOCKS, 256, 0, stream>>>(
            h_ops, weights, combined, row, row_ptr, total4, K, E, N);
        spmm_bf16_w8_kernel<<<spmm_blocks, 256, 0, stream>>>(combined, vals, row_ptr, col,
                                                             weights, out, N, K);
    } else if (ws_size >= need_f32) {
        float* combined = (float*)d_ws;
        int total4 = total / 4;
        combine_kernel<<<2048, 256, 0, stream>>>(h_ops, weights, combined, total4, K);
        spmm_kernel_bs<<<spmm_blocks, 256, 0, stream>>>(combined, vals, row, col,
                                                        weights, out, N, E, K);
    } else {
        spmm_fused_kernel<<<spmm_blocks, 256, 0, stream>>>(h_ops, vals, row, col, weights,
                                                           out, N, E, K, (size_t)total);
    }
}